// Round 1
// baseline (115.425 us; speedup 1.0000x reference)
//
#include <hip/hip_runtime.h>

// Bilateral filter 5x5, sigma_spatial=1.5, sigma_color=0.1, reflect pad.
// Input: [2,3,1024,1024] fp32 -> treated as 6 independent HxW images.
// Block (64,4) computes a 64x16 output tile; LDS-staged 68x20 input tile.

#define TX 64
#define TY 16
#define BY 4
#define PAD 2
#define LW (TX + 2 * PAD)   // 68
#define LH (TY + 2 * PAD)   // 20

__global__ __launch_bounds__(256) void bilateral_kernel(
    const float* __restrict__ in, float* __restrict__ out, int H, int W) {
    const int z  = blockIdx.z;
    const int x0 = blockIdx.x * TX;
    const int y0 = blockIdx.y * TY;
    const int tx = threadIdx.x;
    const int ty = threadIdx.y;
    const int tid = ty * TX + tx;

    __shared__ float tile[LH * LW];

    const float* img = in + (size_t)z * H * W;

    // Cooperative halo load with reflect indexing (pad=2, single reflection).
    for (int idx = tid; idx < LH * LW; idx += TX * BY) {
        int r = idx / LW;
        int c = idx - r * LW;
        int gy = y0 - PAD + r;
        int gx = x0 - PAD + c;
        gy = gy < 0 ? -gy : (gy >= H ? 2 * H - 2 - gy : gy);
        gx = gx < 0 ? -gx : (gx >= W ? 2 * W - 2 - gx : gx);
        tile[idx] = img[(size_t)gy * W + gx];
    }
    __syncthreads();

    // Spatial Gaussian k1 (normalized), computed per-thread (5 exps, cheap).
    float k1[5];
    float s = 0.f;
#pragma unroll
    for (int i = 0; i < 5; ++i) {
        float x = (float)(i - 2) * (1.0f / 1.5f);
        k1[i] = __expf(-0.5f * x * x);
        s += k1[i];
    }
    float inv_s = 1.0f / s;
#pragma unroll
    for (int i = 0; i < 5; ++i) k1[i] *= inv_s;

    // Each thread computes TY/BY = 4 rows (ty, ty+4, ty+8, ty+12).
#pragma unroll
    for (int q = 0; q < TY / BY; ++q) {
        const int ly = ty + q * BY;          // local output row 0..15
        const float ctr = tile[(ly + PAD) * LW + (tx + PAD)];
        float wsum = 0.f;
        float vsum = 0.f;
#pragma unroll
        for (int i = 0; i < 5; ++i) {
            const float ki = k1[i];
#pragma unroll
            for (int j = 0; j < 5; ++j) {
                const float p = tile[(ly + i) * LW + (tx + j)];
                const float d = (p - ctr) * 10.0f;          // / sigma_color
                const float w = ki * k1[j] * __expf(-0.5f * d * d);
                wsum += w;
                vsum += w * p;
            }
        }
        const int gy = y0 + ly;
        out[((size_t)z * H + gy) * W + (x0 + tx)] = vsum / (wsum + 1e-8f);
    }
}

extern "C" void kernel_launch(void* const* d_in, const int* in_sizes, int n_in,
                              void* d_out, int out_size, void* d_ws, size_t ws_size,
                              hipStream_t stream) {
    const float* img = (const float*)d_in[0];
    float* out = (float*)d_out;

    const int B = 2, C = 3, H = 1024, W = 1024;
    dim3 block(TX, BY, 1);
    dim3 grid(W / TX, H / TY, B * C);   // 16 x 64 x 6 = 6144 blocks
    bilateral_kernel<<<grid, block, 0, stream>>>(img, out, H, W);
}

// Round 2
// 106.534 us; speedup vs baseline: 1.0835x; 1.0835x over previous
//
#include <hip/hip_runtime.h>

// Bilateral 5x5, sigma=1.5 (spatial), 0.1 (color), reflect pad.
// [2,3,1024,1024] fp32 = 6 independent 1024x1024 images.
// Block (64,4): 64x64 tile in LDS; each thread computes a 16-tall column
// with a 5x5 register sliding window (5 new LDS reads per output row).
// Weights folded to exp2 domain: w = exp2(-(t*S)^2 + log2(k2ij)),
// S = sqrt(50*log2(e)), so per tap = sub,mul,fma,v_exp,add,fma.

#define TX 64
#define TY 64
#define BY 4
#define RPT (TY / BY)     // 16 output rows per thread
#define PAD 2
#define LW (TX + 2 * PAD) // 68
#define LH (TY + 2 * PAD) // 68

#if __has_builtin(__builtin_amdgcn_exp2f)
#define EXP2(x) __builtin_amdgcn_exp2f(x)
#else
#define EXP2(x) exp2f(x)
#endif

__global__ __launch_bounds__(256) void bilateral_kernel(
    const float* __restrict__ in, float* __restrict__ out, int H, int W)
{
    const int z  = blockIdx.z;
    const int x0 = blockIdx.x * TX;
    const int y0 = blockIdx.y * TY;
    const int tx = threadIdx.x;
    const int ty = threadIdx.y;
    const int tid = ty * TX + tx;

    __shared__ float tile[LH * LW];
    const float* img = in + (size_t)z * H * W;

    // Cooperative halo load, reflect indexing (pad=2, single reflection).
    for (int idx = tid; idx < LH * LW; idx += TX * BY) {
        int r = idx / LW;
        int c = idx - r * LW;
        int gy = y0 - PAD + r;
        int gx = x0 - PAD + c;
        gy = gy < 0 ? -gy : (gy >= H ? 2 * H - 2 - gy : gy);
        gx = gx < 0 ? -gx : (gx >= W ? 2 * W - 2 - gx : gx);
        tile[idx] = img[(size_t)gy * W + gx];
    }
    __syncthreads();

    // Normalized spatial gaussian; move to log2 domain for folding.
    float k1[5];
    float s = 0.f;
#pragma unroll
    for (int i = 0; i < 5; ++i) {
        float x = (float)(i - 2) * (1.0f / 1.5f);
        k1[i] = __expf(-0.5f * x * x);
        s += k1[i];
    }
    const float inv_s = 1.0f / s;
    float l1[5];
#pragma unroll
    for (int i = 0; i < 5; ++i) l1[i] = __log2f(k1[i] * inv_s);
    float lk2[5][5];
#pragma unroll
    for (int i = 0; i < 5; ++i)
#pragma unroll
        for (int j = 0; j < 5; ++j) lk2[i][j] = l1[i] + l1[j];
    const float K2C = EXP2(lk2[2][2]);      // exact center weight
    const float S = 8.49321794f;            // sqrt(50 * log2(e))

    const int ly0 = ty * RPT;               // first output row (tile coords)

    // Preload window rows 0..3 (tile rows ly0 .. ly0+3).
    float win[5][5];
#pragma unroll
    for (int r = 0; r < 4; ++r)
#pragma unroll
        for (int j = 0; j < 5; ++j)
            win[r][j] = tile[(ly0 + r) * LW + tx + j];

#pragma unroll
    for (int q = 0; q < RPT; ++q) {
        // Fill the incoming bottom row (tile row ly0+q+4).
        const int fill = (q + 4) % 5;
#pragma unroll
        for (int j = 0; j < 5; ++j)
            win[fill][j] = tile[(ly0 + q + 4) * LW + tx + j];

        const float ctr = win[(q + 2) % 5][2];
        float wsum = K2C;
        float vsum = K2C * ctr;
#pragma unroll
        for (int i = 0; i < 5; ++i) {
            const int ri = (q + i) % 5;
#pragma unroll
            for (int j = 0; j < 5; ++j) {
                if (i == 2 && j == 2) continue;   // center handled exactly
                const float p = win[ri][j];
                const float u = (p - ctr) * S;
                const float w = EXP2(__builtin_fmaf(-u, u, lk2[i][j]));
                wsum += w;
                vsum = __builtin_fmaf(w, p, vsum);
            }
        }
        const float r = __builtin_amdgcn_rcpf(wsum + 1e-8f);
        out[((size_t)z * H + (y0 + ly0 + q)) * W + (x0 + tx)] = vsum * r;
    }
}

extern "C" void kernel_launch(void* const* d_in, const int* in_sizes, int n_in,
                              void* d_out, int out_size, void* d_ws, size_t ws_size,
                              hipStream_t stream) {
    const float* img = (const float*)d_in[0];
    float* out = (float*)d_out;

    const int B = 2, C = 3, H = 1024, W = 1024;
    dim3 block(TX, BY, 1);
    dim3 grid(W / TX, H / TY, B * C);   // 16 x 16 x 6 = 1536 blocks
    bilateral_kernel<<<grid, block, 0, stream>>>(img, out, H, W);
}

// Round 3
// 102.138 us; speedup vs baseline: 1.1301x; 1.0430x over previous
//
#include <hip/hip_runtime.h>

// Bilateral 5x5, sigma_spatial=1.5, sigma_color=0.1, reflect pad.
// [2,3,1024,1024] fp32 = 6 independent 1024x1024 images.
// Block (64,4): 64x32 output tile, 68x36 LDS tile PRE-SCALED by
// S = sqrt(50*log2(e)) so each tap is: sub, fma(-u,u,LK2), exp2, add, fma.
// Each thread: 8-row column, processed 2 rows/iter with a 6-row register
// window (2 independent outputs x 2 partial accumulators = 4 chains of ILP).
// w = exp2(-(S*(p-c))^2 + log2(k2ij)); out = vsum_s * rcp(S*wsum + S*eps).

#define TX 64
#define TY 32
#define BY 4
#define RPT (TY / BY)     // 8 output rows per thread
#define PAD 2
#define LW (TX + 2 * PAD) // 68
#define LH (TY + 2 * PAD) // 36

#if __has_builtin(__builtin_amdgcn_exp2f)
#define EXP2(x) __builtin_amdgcn_exp2f(x)
#else
#define EXP2(x) exp2f(x)
#endif

// log2 of normalized 1-D gaussian k1 (sigma=1.5, k=5), compile-time:
// k1 = {0.1200783, 0.2338806, 0.2920817, ...} (symmetric)
__device__ __constant__ const float d_dummy = 0.f; // (unused; keeps file shape)

__global__ __launch_bounds__(256) void bilateral_kernel(
    const float* __restrict__ in, float* __restrict__ out, int H, int W)
{
    const int z  = blockIdx.z;
    const int x0 = blockIdx.x * TX;
    const int y0 = blockIdx.y * TY;
    const int tx = threadIdx.x;
    const int ty = threadIdx.y;
    const int tid = ty * TX + tx;

    const float S    = 8.49321794f;     // sqrt(50 * log2(e))
    const float SEPS = 8.49321794e-8f;  // S * 1e-8

    __shared__ float tile[LH * LW];
    const float* img = in + (size_t)z * H * W;

    // Cooperative halo load (reflect, pad=2), pre-scaled by S.
    for (int idx = tid; idx < LH * LW; idx += TX * BY) {
        int r = idx / LW;
        int c = idx - r * LW;
        int gy = y0 - PAD + r;
        int gx = x0 - PAD + c;
        gy = gy < 0 ? -gy : (gy >= H ? 2 * H - 2 - gy : gy);
        gx = gx < 0 ? -gx : (gx >= W ? 2 * W - 2 - gx : gx);
        tile[idx] = img[(size_t)gy * W + gx] * S;
    }
    __syncthreads();

    // Compile-time log2(k1_normalized); lk2[i][j] = L[i]+L[j] folds to
    // 6 distinct SGPR constants under full unroll.
    const float L[5] = {-3.0579510f, -2.0961485f, -1.7755560f,
                        -2.0961485f, -3.0579510f};
    const float K2C = 0.08531170f;      // k1n[2]^2 exact center weight

    const int ly0 = ty * RPT;           // first output row in tile coords

    // 6-row circular register window (scaled values).
    float win[6][5];
#pragma unroll
    for (int r = 0; r < 4; ++r)
#pragma unroll
        for (int j = 0; j < 5; ++j)
            win[r][j] = tile[(ly0 + r) * LW + tx + j];

#pragma unroll
    for (int q = 0; q < RPT; q += 2) {
        // Load the two incoming rows (tile rows ly0+q+4, ly0+q+5).
        const int sA = (q + 4) % 6, sB = (q + 5) % 6;
#pragma unroll
        for (int j = 0; j < 5; ++j)
            win[sA][j] = tile[(ly0 + q + 4) * LW + tx + j];
#pragma unroll
        for (int j = 0; j < 5; ++j)
            win[sB][j] = tile[(ly0 + q + 5) * LW + tx + j];

        const float c0 = win[(q + 2) % 6][2];   // scaled centers
        const float c1 = win[(q + 3) % 6][2];

        float w0a = K2C, v0a = K2C * c0, w0b = 0.f, v0b = 0.f;
        float w1a = K2C, v1a = K2C * c1, w1b = 0.f, v1b = 0.f;

#pragma unroll
        for (int i = 0; i < 5; ++i) {
            const int r0 = (q + i) % 6;         // row i of out0's window
            const int r1 = (q + 1 + i) % 6;     // row i of out1's window
#pragma unroll
            for (int j = 0; j < 5; ++j) {
                const float lk2 = L[i] + L[j];  // compile-time constant
                if (!(i == 2 && j == 2)) {
                    const float p = win[r0][j];
                    const float u = p - c0;
                    const float w = EXP2(__builtin_fmaf(-u, u, lk2));
                    if (((i * 5 + j) & 1) == 0) { w0a += w; v0a = __builtin_fmaf(w, p, v0a); }
                    else                        { w0b += w; v0b = __builtin_fmaf(w, p, v0b); }
                }
                if (!(i == 2 && j == 2)) {
                    const float p = win[r1][j];
                    const float u = p - c1;
                    const float w = EXP2(__builtin_fmaf(-u, u, lk2));
                    if (((i * 5 + j) & 1) == 0) { w1a += w; v1a = __builtin_fmaf(w, p, v1a); }
                    else                        { w1b += w; v1b = __builtin_fmaf(w, p, v1b); }
                }
            }
        }
        const float w0 = w0a + w0b, v0 = v0a + v0b;
        const float w1 = w1a + w1b, v1 = v1a + v1b;
        const float r0v = __builtin_amdgcn_rcpf(__builtin_fmaf(S, w0, SEPS));
        const float r1v = __builtin_amdgcn_rcpf(__builtin_fmaf(S, w1, SEPS));
        const size_t base = ((size_t)z * H + (y0 + ly0 + q)) * W + (x0 + tx);
        out[base]     = v0 * r0v;
        out[base + W] = v1 * r1v;
    }
}

extern "C" void kernel_launch(void* const* d_in, const int* in_sizes, int n_in,
                              void* d_out, int out_size, void* d_ws, size_t ws_size,
                              hipStream_t stream) {
    const float* img = (const float*)d_in[0];
    float* out = (float*)d_out;

    const int B = 2, C = 3, H = 1024, W = 1024;
    dim3 block(TX, BY, 1);
    dim3 grid(W / TX, H / TY, B * C);   // 16 x 32 x 6 = 3072 blocks
    bilateral_kernel<<<grid, block, 0, stream>>>(img, out, H, W);
}

// Round 4
// 93.628 us; speedup vs baseline: 1.2328x; 1.0909x over previous
//
#include <hip/hip_runtime.h>

// Bilateral 5x5, sigma_spatial=1.5, sigma_color=0.1, reflect pad.
// [2,3,1024,1024] fp32 = 6 independent 1024x1024 images.
//
// Weight w = exp2(-u^2 + lk2_ij) computed with a Schraudolph-style
// integer-bit exp2 (minimax shift 0.043 => rel err within +/-3%, which
// largely cancels under the bilateral normalization):
//   tile pre-scaled by Ssc = sqrt(2^23 * 50*log2(e)) so
//   t = fma(-u', u', Cij),  Cij = 2^23*lk2_ij + (127-0.043)*2^23
//   w = bitcast<float>((int)t)          // t > 0 always for inputs in [0,1]
// Tap cost: 5 full-rate VALU ops, zero transcendentals.
//
// Block (64,4): 64x16 output tile (grid 6144 = 24 blocks/CU = 3 clean
// rounds of 8 resident). Each thread: 4-row column, 2 rows/iter with a
// 6-row register window; 4 independent accumulator chains for ILP.

#define TX 64
#define TY 16
#define BY 4
#define RPT (TY / BY)     // 4 output rows per thread
#define PAD 2
#define LW (TX + 2 * PAD) // 68
#define LH (TY + 2 * PAD) // 20

__global__ __launch_bounds__(256) void bilateral_kernel(
    const float* __restrict__ in, float* __restrict__ out, int H, int W)
{
    const int z  = blockIdx.z;
    const int x0 = blockIdx.x * TX;
    const int y0 = blockIdx.y * TY;
    const int tx = threadIdx.x;
    const int ty = threadIdx.y;
    const int tid = ty * TX + tx;

    // Ssc = sqrt(2^23 * 50 * log2(e));  SEPS = Ssc * 1e-8
    const float Ssc  = 24598.9869f;
    const float SEPS = 2.45989869e-4f;

    __shared__ float tile[LH * LW];
    const float* img = in + (size_t)z * H * W;

    // Cooperative halo load (reflect, pad=2), pre-scaled by Ssc.
    for (int idx = tid; idx < LH * LW; idx += TX * BY) {
        int r = idx / LW;
        int c = idx - r * LW;
        int gy = y0 - PAD + r;
        int gx = x0 - PAD + c;
        gy = gy < 0 ? -gy : (gy >= H ? 2 * H - 2 - gy : gy);
        gx = gx < 0 ? -gx : (gx >= W ? 2 * W - 2 - gx : gx);
        tile[idx] = img[(size_t)gy * W + gx] * Ssc;
    }
    __syncthreads();

    // log2 of normalized 1-D spatial gaussian (sigma=1.5, k=5).
    constexpr double Ld[5] = {-3.0580100, -2.0962162, -1.7756103,
                              -2.0962162, -3.0580100};
    constexpr double A  = 8388608.0;           // 2^23
    constexpr double C0 = 1064992506.0;        // (127 - 0.043) * 2^23
    const float K2C = 0.0853118f;              // exact center weight k1n[2]^2

    const int ly0 = ty * RPT;                  // first output row (tile coords)

    // 6-row circular register window (scaled values).
    float win[6][5];
#pragma unroll
    for (int r = 0; r < 4; ++r)
#pragma unroll
        for (int j = 0; j < 5; ++j)
            win[r][j] = tile[(ly0 + r) * LW + tx + j];

#pragma unroll
    for (int q = 0; q < RPT; q += 2) {
        // Load the two incoming rows (tile rows ly0+q+4, ly0+q+5).
        const int sA = (q + 4) % 6, sB = (q + 5) % 6;
#pragma unroll
        for (int j = 0; j < 5; ++j)
            win[sA][j] = tile[(ly0 + q + 4) * LW + tx + j];
#pragma unroll
        for (int j = 0; j < 5; ++j)
            win[sB][j] = tile[(ly0 + q + 5) * LW + tx + j];

        const float c0 = win[(q + 2) % 6][2];   // scaled centers
        const float c1 = win[(q + 3) % 6][2];

        float w0a = K2C, v0a = K2C * c0, w0b = 0.f, v0b = 0.f;
        float w1a = K2C, v1a = K2C * c1, w1b = 0.f, v1b = 0.f;

#pragma unroll
        for (int i = 0; i < 5; ++i) {
            const int r0 = (q + i) % 6;         // row i of out0's window
            const int r1 = (q + 1 + i) % 6;     // row i of out1's window
#pragma unroll
            for (int j = 0; j < 5; ++j) {
                if (i == 2 && j == 2) continue; // center handled exactly
                const float Cij = (float)(A * (Ld[i] + Ld[j]) + C0);
                {
                    const float p = win[r0][j];
                    const float u = p - c0;
                    const float t = __builtin_fmaf(-u, u, Cij);
                    const float w = __builtin_bit_cast(float, (int)t);
                    if (((i * 5 + j) & 1) == 0) { w0a += w; v0a = __builtin_fmaf(w, p, v0a); }
                    else                        { w0b += w; v0b = __builtin_fmaf(w, p, v0b); }
                }
                {
                    const float p = win[r1][j];
                    const float u = p - c1;
                    const float t = __builtin_fmaf(-u, u, Cij);
                    const float w = __builtin_bit_cast(float, (int)t);
                    if (((i * 5 + j) & 1) == 0) { w1a += w; v1a = __builtin_fmaf(w, p, v1a); }
                    else                        { w1b += w; v1b = __builtin_fmaf(w, p, v1b); }
                }
            }
        }
        const float w0 = w0a + w0b, v0 = v0a + v0b;
        const float w1 = w1a + w1b, v1 = v1a + v1b;
        const float r0v = __builtin_amdgcn_rcpf(__builtin_fmaf(Ssc, w0, SEPS));
        const float r1v = __builtin_amdgcn_rcpf(__builtin_fmaf(Ssc, w1, SEPS));
        const size_t base = ((size_t)z * H + (y0 + ly0 + q)) * W + (x0 + tx);
        out[base]     = v0 * r0v;
        out[base + W] = v1 * r1v;
    }
}

extern "C" void kernel_launch(void* const* d_in, const int* in_sizes, int n_in,
                              void* d_out, int out_size, void* d_ws, size_t ws_size,
                              hipStream_t stream) {
    const float* img = (const float*)d_in[0];
    float* out = (float*)d_out;

    const int B = 2, C = 3, H = 1024, W = 1024;
    dim3 block(TX, BY, 1);
    dim3 grid(W / TX, H / TY, B * C);   // 16 x 64 x 6 = 6144 blocks
    bilateral_kernel<<<grid, block, 0, stream>>>(img, out, H, W);
}